// Round 3
// baseline (34844.745 us; speedup 1.0000x reference)
//
#include <hip/hip_runtime.h>
#include <stdint.h>

// ---------------- pos-emb fill: x = table0[px] + table1[py] ----------------
__global__ __launch_bounds__(256) void k_posemb(const int* __restrict__ pos,
                                                const float* __restrict__ ptab,
                                                float* __restrict__ x) {
  int row = blockIdx.x, tid = threadIdx.x;
  int p0 = pos[(size_t)row * 2], p1 = pos[(size_t)row * 2 + 1];
  bool pad = (p0 == -1) && (p1 == -1);
  int px = p0 > 0 ? p0 : 0, py = p1 > 0 ? p1 : 0;
  float4 a = ((const float4*)(ptab + (size_t)px * 1024))[tid];
  float4 b = ((const float4*)(ptab + 65536 + (size_t)py * 1024))[tid];
  float4 o;
  o.x = pad ? 0.f : a.x + b.x;
  o.y = pad ? 0.f : a.y + b.y;
  o.z = pad ? 0.f : a.z + b.z;
  o.w = pad ? 0.f : a.w + b.w;
  ((float4*)(x + (size_t)row * 1024))[tid] = o;
}

// ---------------- RMSNorm over D=1024, f32 -> f32 ----------------
__global__ __launch_bounds__(256) void k_rmsnorm32(const float* __restrict__ x,
                                                   const float* __restrict__ scale,
                                                   float* __restrict__ out) {
  __shared__ float wsum[4];
  int row = blockIdx.x, tid = threadIdx.x;
  float4 v = ((const float4*)(x + (size_t)row * 1024))[tid];
  float ss = v.x * v.x + v.y * v.y + v.z * v.z + v.w * v.w;
  for (int m = 1; m < 64; m <<= 1) ss += __shfl_xor(ss, m);
  if ((tid & 63) == 0) wsum[tid >> 6] = ss;
  __syncthreads();
  float tot = wsum[0] + wsum[1] + wsum[2] + wsum[3];
  float r = rsqrtf(tot * (1.f / 1024.f) + 1e-6f);
  float4 sc = ((const float4*)scale)[tid];
  float4 o;
  o.x = v.x * r * sc.x;
  o.y = v.y * r * sc.y;
  o.z = v.z * r * sc.z;
  o.w = v.w * r * sc.w;
  ((float4*)(out + (size_t)row * 1024))[tid] = o;
}

// ---------------- x += RMSNorm(t) * scale ----------------
__global__ __launch_bounds__(256) void k_addrms32(float* __restrict__ x,
                                                  const float* __restrict__ t,
                                                  const float* __restrict__ scale) {
  __shared__ float wsum[4];
  int row = blockIdx.x, tid = threadIdx.x;
  float4 v = ((const float4*)(t + (size_t)row * 1024))[tid];
  float ss = v.x * v.x + v.y * v.y + v.z * v.z + v.w * v.w;
  for (int m = 1; m < 64; m <<= 1) ss += __shfl_xor(ss, m);
  if ((tid & 63) == 0) wsum[tid >> 6] = ss;
  __syncthreads();
  float tot = wsum[0] + wsum[1] + wsum[2] + wsum[3];
  float r = rsqrtf(tot * (1.f / 1024.f) + 1e-6f);
  float4 sc = ((const float4*)scale)[tid];
  float4 xv = ((const float4*)(x + (size_t)row * 1024))[tid];
  xv.x += v.x * r * sc.x;
  xv.y += v.y * r * sc.y;
  xv.z += v.z * r * sc.z;
  xv.w += v.w * r * sc.w;
  ((float4*)(x + (size_t)row * 1024))[tid] = xv;
}

// ---------------- per-head RMSNorm (+ optional 2D RoPE), f32 -> f32 ----------------
template <bool ROPE>
__global__ __launch_bounds__(256) void k_qknorm32(const float* __restrict__ t,
                                                  const float* __restrict__ scale,
                                                  const int* __restrict__ pos,
                                                  float* __restrict__ out) {
  __shared__ float xs[1024];
  __shared__ float rr[16];
  int row = blockIdx.x, tid = threadIdx.x;
  float4 v = ((const float4*)(t + (size_t)row * 1024))[tid];
  ((float4*)xs)[tid] = v;
  __syncthreads();
  if (tid < 16) {
    float s = 0.f;
    for (int j = 0; j < 64; ++j) { float xv = xs[tid * 64 + j]; s += xv * xv; }
    rr[tid] = rsqrtf(s * (1.f / 64.f) + 1e-6f);
  }
  __syncthreads();
  int head = tid >> 4, lp = tid & 15;
  float r = rr[head];
  int p0 = 0, p1 = 0;
  if (ROPE) {
    p0 = pos[(size_t)row * 2]; p1 = pos[(size_t)row * 2 + 1];
    p0 = p0 > 0 ? p0 : 0; p1 = p1 > 0 ? p1 : 0;
  }
  float o4[4];
#pragma unroll
  for (int j = 0; j < 4; ++j) {
    int hh = lp * 4 + j;
    float sc = scale ? scale[hh] : 1.f;
    float nv = xs[head * 64 + hh] * r * sc;
    if (ROPE) {
      int s = hh & 31;
      int f = s & 15;
      float posv = (hh < 32) ? (float)p0 : (float)p1;
      float inv = powf(10000.f, -(float)f * (1.f / 16.f));
      float ang = posv * inv;
      float sn = sinf(ang), cs = cosf(ang);
      int ph = (s < 16) ? hh + 16 : hh - 16;
      float psc = scale ? scale[ph] : 1.f;
      float pv = xs[head * 64 + ph] * r * psc;
      nv = (s < 16) ? (nv * cs - pv * sn) : (nv * cs + pv * sn);
    }
    o4[j] = nv;
  }
  float* orow = out + (size_t)row * 1024 + tid * 4;
  orow[0] = o4[0]; orow[1] = o4[1]; orow[2] = o4[2]; orow[3] = o4[3];
}

// ---------------- pure-f32 64x64-tile LDS GEMM (A[M][K] * B[K][N]) ----------------
enum { EPI_F32 = 0, EPI_ADDF32 = 1, EPI_GELU = 2, EPI_MUL = 3 };

template <int EPI, bool PIXT>
__global__ __launch_bounds__(256) void k_gemm32(const float* __restrict__ A,
                                                const float* __restrict__ B,
                                                float* C,
                                                const float* Mul,
                                                int K, int N) {
  __shared__ float As[64][20];
  __shared__ float Bs[16][68];
  const int tid = threadIdx.x;
  const int m0 = blockIdx.y << 6, n0 = blockIdx.x << 6;
  const int tx = tid & 15, ty = tid >> 4;
  const int ar = tid >> 2, ac4 = (tid & 3) << 2;
  const int br = tid >> 4, bc4 = (tid & 15) << 2;
  float c[4][4] = {};

  for (int k0 = 0; k0 < K; k0 += 16) {
    float4 av = *(const float4*)(A + (size_t)(m0 + ar) * K + k0 + ac4);
    if (PIXT) {
      av.x = 2.f * (av.x - 0.5f); av.y = 2.f * (av.y - 0.5f);
      av.z = 2.f * (av.z - 0.5f); av.w = 2.f * (av.w - 0.5f);
    }
    float4 bv = *(const float4*)(B + (size_t)(k0 + br) * N + n0 + bc4);
    __syncthreads();
    As[ar][ac4 + 0] = av.x; As[ar][ac4 + 1] = av.y;
    As[ar][ac4 + 2] = av.z; As[ar][ac4 + 3] = av.w;
    Bs[br][bc4 + 0] = bv.x; Bs[br][bc4 + 1] = bv.y;
    Bs[br][bc4 + 2] = bv.z; Bs[br][bc4 + 3] = bv.w;
    __syncthreads();
#pragma unroll
    for (int kk = 0; kk < 16; ++kk) {
      float a0 = As[ty * 4 + 0][kk], a1 = As[ty * 4 + 1][kk];
      float a2 = As[ty * 4 + 2][kk], a3 = As[ty * 4 + 3][kk];
      float b0 = Bs[kk][tx * 4 + 0], b1 = Bs[kk][tx * 4 + 1];
      float b2 = Bs[kk][tx * 4 + 2], b3 = Bs[kk][tx * 4 + 3];
      c[0][0] += a0 * b0; c[0][1] += a0 * b1; c[0][2] += a0 * b2; c[0][3] += a0 * b3;
      c[1][0] += a1 * b0; c[1][1] += a1 * b1; c[1][2] += a1 * b2; c[1][3] += a1 * b3;
      c[2][0] += a2 * b0; c[2][1] += a2 * b1; c[2][2] += a2 * b2; c[2][3] += a2 * b3;
      c[3][0] += a3 * b0; c[3][1] += a3 * b1; c[3][2] += a3 * b2; c[3][3] += a3 * b3;
    }
  }

#pragma unroll
  for (int i = 0; i < 4; ++i) {
#pragma unroll
    for (int j = 0; j < 4; ++j) {
      int gr = m0 + ty * 4 + i;
      int gc = n0 + tx * 4 + j;
      size_t idx = (size_t)gr * N + gc;
      float val = c[i][j];
      if (EPI == EPI_F32) {
        C[idx] = val;
      } else if (EPI == EPI_ADDF32) {
        C[idx] += val;
      } else if (EPI == EPI_GELU) {
        float x3 = val * val * val;
        float g = 0.5f * val * (1.f + tanhf(0.7978845608028654f * (val + 0.044715f * x3)));
        C[idx] = g;
      } else {
        C[idx] = val * Mul[idx];
      }
    }
  }
}

// ---------------- simple exact attention, f32: block = (b, head, one q-row) ----------------
__global__ __launch_bounds__(256) void k_attn32(const float* __restrict__ q,
                                                const float* __restrict__ k,
                                                const float* __restrict__ v,
                                                float* __restrict__ o) {
  __shared__ float qs[64];
  __shared__ float ps[1024];
  __shared__ float red[8];
  __shared__ float part[16][64];
  const int tid = threadIdx.x;
  const int l = blockIdx.x;
  const int bh = blockIdx.y;
  const int b = bh >> 4, n = bh & 15;
  const size_t base = (size_t)b * 1048576 + (size_t)n * 64;
  const size_t qoff = base + (size_t)l * 1024;
  if (tid < 64) qs[tid] = q[qoff + tid];
  __syncthreads();

  float sv[4];
  float lmax = -3.0e38f;
#pragma unroll
  for (int j = 0; j < 4; ++j) {
    int kk = (tid << 2) + j;
    const float* krow = k + base + (size_t)kk * 1024;
    float s = 0.f;
#pragma unroll
    for (int c = 0; c < 64; c += 4) {
      float4 kv = *(const float4*)(krow + c);
      s += qs[c + 0] * kv.x + qs[c + 1] * kv.y + qs[c + 2] * kv.z + qs[c + 3] * kv.w;
    }
    sv[j] = s;
    lmax = fmaxf(lmax, s);
  }
  for (int m = 1; m < 64; m <<= 1) lmax = fmaxf(lmax, __shfl_xor(lmax, m));
  if ((tid & 63) == 0) red[tid >> 6] = lmax;
  __syncthreads();
  float smax = fmaxf(fmaxf(red[0], red[1]), fmaxf(red[2], red[3]));
  float lsum = 0.f;
#pragma unroll
  for (int j = 0; j < 4; ++j) {
    float p = expf(sv[j] - smax);
    ps[(tid << 2) + j] = p;
    lsum += p;
  }
  for (int m = 1; m < 64; m <<= 1) lsum += __shfl_xor(lsum, m);
  if ((tid & 63) == 0) red[4 + (tid >> 6)] = lsum;
  __syncthreads();
  float ssum = red[4] + red[5] + red[6] + red[7];

  const int kp = tid >> 4, hg = tid & 15;
  float a0 = 0.f, a1 = 0.f, a2 = 0.f, a3 = 0.f;
  for (int kk = kp << 6; kk < (kp << 6) + 64; ++kk) {
    float p = ps[kk];
    float4 vv = *(const float4*)(v + base + (size_t)kk * 1024 + (hg << 2));
    a0 += p * vv.x; a1 += p * vv.y; a2 += p * vv.z; a3 += p * vv.w;
  }
  part[kp][hg * 4 + 0] = a0;
  part[kp][hg * 4 + 1] = a1;
  part[kp][hg * 4 + 2] = a2;
  part[kp][hg * 4 + 3] = a3;
  __syncthreads();
  if (tid < 64) {
    float s = 0.f;
#pragma unroll
    for (int i = 0; i < 16; ++i) s += part[i][tid];
    o[qoff + tid] = s / ssum;
  }
}

// ---------------- 4x4 pooling + mask ----------------
__global__ __launch_bounds__(256) void k_pool(const float* __restrict__ x,
                                              const int* __restrict__ pos,
                                              float* __restrict__ out,
                                              float* __restrict__ maskout) {
  __shared__ int smax[4];
  __shared__ int kidx_s[1024];
  const int blk = blockIdx.x;
  const int b = blk >> 6, oidx = blk & 63;
  const int tid = threadIdx.x;
  int mx = 0;
  for (int l = tid; l < 1024; l += 256) {
    int p0 = pos[((size_t)b * 1024 + l) * 2];
    mx = max(mx, p0 > 0 ? p0 : 0);
  }
  for (int m = 1; m < 64; m <<= 1) mx = max(mx, __shfl_xor(mx, m));
  if ((tid & 63) == 0) smax[tid >> 6] = mx;
  __syncthreads();
  int maxx = max(max(smax[0], smax[1]), max(smax[2], smax[3])) + 1;
  int mk = maxx >> 2;
  for (int l = tid; l < 1024; l += 256) {
    int p0 = pos[((size_t)b * 1024 + l) * 2];
    int p1 = pos[((size_t)b * 1024 + l) * 2 + 1];
    int c0 = p0 > 0 ? p0 : 0, c1 = p1 > 0 ? p1 : 0;
    int pad = (p0 == -1 && p1 == -1) ? 1 : 0;
    kidx_s[l] = ((c0 >> 2) + mk * (c1 >> 2)) | (pad << 16);
  }
  __syncthreads();
  float ax = 0.f, ay = 0.f, az = 0.f, aw = 0.f;
  int cnt = 0;
  for (int l = 0; l < 1024; ++l) {
    int ki = kidx_s[l];
    if ((ki & 0xffff) == oidx) {
      cnt++;
      if (!(ki >> 16)) {
        float4 xv = ((const float4*)(x + ((size_t)b * 1024 + l) * 1024))[tid];
        ax += xv.x; ay += xv.y; az += xv.z; aw += xv.w;
      }
    }
  }
  float4 res;
  res.x = ax * 2.0f; res.y = ay * 2.0f; res.z = az * 2.0f; res.w = aw * 2.0f;
  ((float4*)(out + ((size_t)b * 64 + oidx) * 1024))[tid] = res;
  if (tid == 0) maskout[b * 64 + oidx] = (cnt > 0) ? 1.0f : 0.0f;
}

// ---------------- host launch ----------------
extern "C" void kernel_launch(void* const* d_in, const int* in_sizes, int n_in,
                              void* d_out, int out_size, void* d_ws, size_t ws_size,
                              hipStream_t stream) {
  const float* pix = (const float*)d_in[0];
  const int* pos = (const int*)d_in[1];
  const float* Win = (const float*)d_in[2];
  const float* ptab = (const float*)d_in[3];
  const float* Wq = (const float*)d_in[4];
  const float* Wk = (const float*)d_in[5];
  const float* Wv = (const float*)d_in[6];
  const float* Wo = (const float*)d_in[7];
  const float* qn = (const float*)d_in[8];
  const float* kn = (const float*)d_in[9];
  const float* pre_attn = (const float*)d_in[10];
  const float* post_attn = (const float*)d_in[11];
  const float* pre_ffw = (const float*)d_in[12];
  const float* post_ffw = (const float*)d_in[13];
  const float* Wg = (const float*)d_in[14];
  const float* Wu = (const float*)d_in[15];
  const float* Wd = (const float*)d_in[16];

  char* w = (char*)d_ws;
  float* x = (float*)w;   w += 16777216;
  float* tmp = (float*)w; w += 16777216;
  float* h = (float*)w;   w += 16777216;
  float* qb = (float*)w;  w += 16777216;
  float* kb = (float*)w;  w += 16777216;
  float* vb = (float*)w;  w += 16777216;
  float* ab = (float*)w;  w += 16777216;
  float* gb = (float*)w;  // 4096*4096*4 = 67108864 bytes

  dim3 blk(256);
  k_posemb<<<4096, blk, 0, stream>>>(pos, ptab, x);
  k_gemm32<EPI_ADDF32, true><<<dim3(16, 64), blk, 0, stream>>>(pix, Win, x, nullptr, 768, 1024);

  for (int i = 0; i < 6; ++i) {
    const float* wq = Wq + (size_t)i * 1048576;
    const float* wk = Wk + (size_t)i * 1048576;
    const float* wv = Wv + (size_t)i * 1048576;
    const float* wo = Wo + (size_t)i * 1048576;
    const float* wg = Wg + (size_t)i * 4194304;
    const float* wu = Wu + (size_t)i * 4194304;
    const float* wd = Wd + (size_t)i * 4194304;

    k_rmsnorm32<<<4096, blk, 0, stream>>>(x, pre_attn + i * 1024, h);
    k_gemm32<EPI_F32, false><<<dim3(16, 64), blk, 0, stream>>>(h, wq, tmp, nullptr, 1024, 1024);
    k_qknorm32<true><<<4096, blk, 0, stream>>>(tmp, qn + i * 64, pos, qb);
    k_gemm32<EPI_F32, false><<<dim3(16, 64), blk, 0, stream>>>(h, wk, tmp, nullptr, 1024, 1024);
    k_qknorm32<true><<<4096, blk, 0, stream>>>(tmp, kn + i * 64, pos, kb);
    k_gemm32<EPI_F32, false><<<dim3(16, 64), blk, 0, stream>>>(h, wv, tmp, nullptr, 1024, 1024);
    k_qknorm32<false><<<4096, blk, 0, stream>>>(tmp, nullptr, pos, vb);
    k_attn32<<<dim3(1024, 64), blk, 0, stream>>>(qb, kb, vb, ab);
    k_gemm32<EPI_F32, false><<<dim3(16, 64), blk, 0, stream>>>(ab, wo, tmp, nullptr, 1024, 1024);
    k_addrms32<<<4096, blk, 0, stream>>>(x, tmp, post_attn + i * 1024);

    k_rmsnorm32<<<4096, blk, 0, stream>>>(x, pre_ffw + i * 1024, h);
    k_gemm32<EPI_GELU, false><<<dim3(64, 64), blk, 0, stream>>>(h, wg, gb, nullptr, 1024, 4096);
    k_gemm32<EPI_MUL, false><<<dim3(64, 64), blk, 0, stream>>>(h, wu, gb, gb, 1024, 4096);
    k_gemm32<EPI_F32, false><<<dim3(16, 64), blk, 0, stream>>>(gb, wd, tmp, nullptr, 4096, 1024);
    k_addrms32<<<4096, blk, 0, stream>>>(x, tmp, post_ffw + i * 1024);
  }

  k_pool<<<256, blk, 0, stream>>>(x, pos, (float*)d_out, (float*)d_out + 262144);
}

// Round 5
// 34519.775 us; speedup vs baseline: 1.0094x; 1.0094x over previous
//
#include <hip/hip_runtime.h>
#include <stdint.h>

typedef unsigned short ushort_t;
using frag8 = __attribute__((ext_vector_type(8))) short;
using f32x4 = __attribute__((ext_vector_type(4))) float;

static __device__ __forceinline__ unsigned short f2bf(float f) {
  union { float f; unsigned u; } v; v.f = f;
  unsigned r = v.u + 0x7fffu + ((v.u >> 16) & 1u);
  return (unsigned short)(r >> 16);
}
static __device__ __forceinline__ float bf2f(unsigned short b) {
  union { unsigned u; float f; } v; v.u = ((unsigned)b) << 16; return v.f;
}

// ---------------- pos-emb fill ----------------
__global__ __launch_bounds__(256) void k_posemb(const int* __restrict__ pos,
                                                const float* __restrict__ ptab,
                                                float* __restrict__ x) {
  int row = blockIdx.x, tid = threadIdx.x;
  int p0 = pos[(size_t)row * 2], p1 = pos[(size_t)row * 2 + 1];
  bool pad = (p0 == -1) && (p1 == -1);
  int px = p0 > 0 ? p0 : 0, py = p1 > 0 ? p1 : 0;
  float4 a = ((const float4*)(ptab + (size_t)px * 1024))[tid];
  float4 b = ((const float4*)(ptab + 65536 + (size_t)py * 1024))[tid];
  float4 o;
  o.x = pad ? 0.f : a.x + b.x;
  o.y = pad ? 0.f : a.y + b.y;
  o.z = pad ? 0.f : a.z + b.z;
  o.w = pad ? 0.f : a.w + b.w;
  ((float4*)(x + (size_t)row * 1024))[tid] = o;
}

// ---------------- RMSNorm D=1024 f32 ----------------
__global__ __launch_bounds__(256) void k_rmsnorm32(const float* __restrict__ x,
                                                   const float* __restrict__ scale,
                                                   float* __restrict__ out) {
  __shared__ float wsum[4];
  int row = blockIdx.x, tid = threadIdx.x;
  float4 v = ((const float4*)(x + (size_t)row * 1024))[tid];
  float ss = v.x * v.x + v.y * v.y + v.z * v.z + v.w * v.w;
  for (int m = 1; m < 64; m <<= 1) ss += __shfl_xor(ss, m);
  if ((tid & 63) == 0) wsum[tid >> 6] = ss;
  __syncthreads();
  float tot = wsum[0] + wsum[1] + wsum[2] + wsum[3];
  float r = rsqrtf(tot * (1.f / 1024.f) + 1e-6f);
  float4 sc = ((const float4*)scale)[tid];
  float4 o;
  o.x = v.x * r * sc.x;
  o.y = v.y * r * sc.y;
  o.z = v.z * r * sc.z;
  o.w = v.w * r * sc.w;
  ((float4*)(out + (size_t)row * 1024))[tid] = o;
}

// ---------------- x += RMSNorm(t)*scale ----------------
__global__ __launch_bounds__(256) void k_addrms32(float* __restrict__ x,
                                                  const float* __restrict__ t,
                                                  const float* __restrict__ scale) {
  __shared__ float wsum[4];
  int row = blockIdx.x, tid = threadIdx.x;
  float4 v = ((const float4*)(t + (size_t)row * 1024))[tid];
  float ss = v.x * v.x + v.y * v.y + v.z * v.z + v.w * v.w;
  for (int m = 1; m < 64; m <<= 1) ss += __shfl_xor(ss, m);
  if ((tid & 63) == 0) wsum[tid >> 6] = ss;
  __syncthreads();
  float tot = wsum[0] + wsum[1] + wsum[2] + wsum[3];
  float r = rsqrtf(tot * (1.f / 1024.f) + 1e-6f);
  float4 sc = ((const float4*)scale)[tid];
  float4 xv = ((const float4*)(x + (size_t)row * 1024))[tid];
  xv.x += v.x * r * sc.x;
  xv.y += v.y * r * sc.y;
  xv.z += v.z * r * sc.z;
  xv.w += v.w * r * sc.w;
  ((float4*)(x + (size_t)row * 1024))[tid] = xv;
}

// ---------------- per-head RMSNorm + RoPE f32 ----------------
template <bool ROPE>
__global__ __launch_bounds__(256) void k_qknorm32(const float* __restrict__ t,
                                                  const float* __restrict__ scale,
                                                  const int* __restrict__ pos,
                                                  float* __restrict__ out) {
  __shared__ float xs[1024];
  __shared__ float rr[16];
  int row = blockIdx.x, tid = threadIdx.x;
  float4 v = ((const float4*)(t + (size_t)row * 1024))[tid];
  ((float4*)xs)[tid] = v;
  __syncthreads();
  if (tid < 16) {
    float s = 0.f;
    for (int j = 0; j < 64; ++j) { float xv = xs[tid * 64 + j]; s += xv * xv; }
    rr[tid] = rsqrtf(s * (1.f / 64.f) + 1e-6f);
  }
  __syncthreads();
  int head = tid >> 4, lp = tid & 15;
  float r = rr[head];
  int p0 = 0, p1 = 0;
  if (ROPE) {
    p0 = pos[(size_t)row * 2]; p1 = pos[(size_t)row * 2 + 1];
    p0 = p0 > 0 ? p0 : 0; p1 = p1 > 0 ? p1 : 0;
  }
  float o4[4];
#pragma unroll
  for (int j = 0; j < 4; ++j) {
    int hh = lp * 4 + j;
    float sc = scale ? scale[hh] : 1.f;
    float nv = xs[head * 64 + hh] * r * sc;
    if (ROPE) {
      int s = hh & 31;
      int f = s & 15;
      float posv = (hh < 32) ? (float)p0 : (float)p1;
      float inv = powf(10000.f, -(float)f * (1.f / 16.f));
      float ang = posv * inv;
      float sn = sinf(ang), cs = cosf(ang);
      int ph = (s < 16) ? hh + 16 : hh - 16;
      float psc = scale ? scale[ph] : 1.f;
      float pv = xs[head * 64 + ph] * r * psc;
      nv = (s < 16) ? (nv * cs - pv * sn) : (nv * cs + pv * sn);
    }
    o4[j] = nv;
  }
  float* orow = out + (size_t)row * 1024 + tid * 4;
  orow[0] = o4[0]; orow[1] = o4[1]; orow[2] = o4[2]; orow[3] = o4[3];
}

// ---------------- pure-f32 64x64 GEMM (known good) ----------------
enum { EPI_F32 = 0, EPI_ADDF32 = 1, EPI_GELU = 2, EPI_MUL = 3, EPI_RAW = 4 };

template <int EPI, bool PIXT>
__global__ __launch_bounds__(256) void k_gemm32(const float* __restrict__ A,
                                                const float* __restrict__ B,
                                                float* C,
                                                const float* Mul,
                                                int K, int N) {
  __shared__ float As[64][20];
  __shared__ float Bs[16][68];
  const int tid = threadIdx.x;
  const int m0 = blockIdx.y << 6, n0 = blockIdx.x << 6;
  const int tx = tid & 15, ty = tid >> 4;
  const int ar = tid >> 2, ac4 = (tid & 3) << 2;
  const int br = tid >> 4, bc4 = (tid & 15) << 2;
  float c[4][4] = {};

  for (int k0 = 0; k0 < K; k0 += 16) {
    float4 av = *(const float4*)(A + (size_t)(m0 + ar) * K + k0 + ac4);
    if (PIXT) {
      av.x = 2.f * (av.x - 0.5f); av.y = 2.f * (av.y - 0.5f);
      av.z = 2.f * (av.z - 0.5f); av.w = 2.f * (av.w - 0.5f);
    }
    float4 bv = *(const float4*)(B + (size_t)(k0 + br) * N + n0 + bc4);
    __syncthreads();
    As[ar][ac4 + 0] = av.x; As[ar][ac4 + 1] = av.y;
    As[ar][ac4 + 2] = av.z; As[ar][ac4 + 3] = av.w;
    Bs[br][bc4 + 0] = bv.x; Bs[br][bc4 + 1] = bv.y;
    Bs[br][bc4 + 2] = bv.z; Bs[br][bc4 + 3] = bv.w;
    __syncthreads();
#pragma unroll
    for (int kk = 0; kk < 16; ++kk) {
      float a0 = As[ty * 4 + 0][kk], a1 = As[ty * 4 + 1][kk];
      float a2 = As[ty * 4 + 2][kk], a3 = As[ty * 4 + 3][kk];
      float b0 = Bs[kk][tx * 4 + 0], b1 = Bs[kk][tx * 4 + 1];
      float b2 = Bs[kk][tx * 4 + 2], b3 = Bs[kk][tx * 4 + 3];
      c[0][0] += a0 * b0; c[0][1] += a0 * b1; c[0][2] += a0 * b2; c[0][3] += a0 * b3;
      c[1][0] += a1 * b0; c[1][1] += a1 * b1; c[1][2] += a1 * b2; c[1][3] += a1 * b3;
      c[2][0] += a2 * b0; c[2][1] += a2 * b1; c[2][2] += a2 * b2; c[2][3] += a2 * b3;
      c[3][0] += a3 * b0; c[3][1] += a3 * b1; c[3][2] += a3 * b2; c[3][3] += a3 * b3;
    }
  }

#pragma unroll
  for (int i = 0; i < 4; ++i) {
#pragma unroll
    for (int j = 0; j < 4; ++j) {
      int gr = m0 + ty * 4 + i;
      int gc = n0 + tx * 4 + j;
      size_t idx = (size_t)gr * N + gc;
      float val = c[i][j];
      if (EPI == EPI_F32) {
        C[idx] = val;
      } else if (EPI == EPI_ADDF32) {
        C[idx] += val;
      } else if (EPI == EPI_GELU) {
        float x3 = val * val * val;
        float g = 0.5f * val * (1.f + tanhf(0.7978845608028654f * (val + 0.044715f * x3)));
        C[idx] = g;
      } else {
        C[idx] = val * Mul[idx];
      }
    }
  }
}

// ---------------- MFMA GEMM under test (EPI_RAW dumps raw acc) ----------------
template <int EPI, bool PIXT>
__global__ __launch_bounds__(256) void k_gemmx(const float* __restrict__ A,
                                               const float* __restrict__ B,
                                               float* C,
                                               const float* Mul,
                                               int K, int N) {
  __shared__ __align__(16) ushort_t Asm[128][40];
  __shared__ __align__(16) ushort_t Bsm[128][40];
  const int tid = threadIdx.x;
  const int m0 = blockIdx.y << 7, n0 = blockIdx.x << 7;
  const int lane = tid & 63;
  const int wm = ((tid >> 7) & 1) * 64;
  const int wn = ((tid >> 6) & 1) * 64;
  const int l15 = lane & 15, lg = lane >> 4;
  const int arow = tid >> 1, acol = (tid & 1) << 4;
  const int bnn = tid & 127, bk0 = (tid >> 7) << 4;
  f32x4 acc[4][4] = {};

  for (int k0 = 0; k0 < K; k0 += 32) {
    const float* ga = A + (size_t)(m0 + arow) * K + (k0 + acol);
    float af32[16];
#pragma unroll
    for (int g = 0; g < 4; ++g) {
      float4 fv = *(const float4*)(ga + g * 4);
      af32[g * 4 + 0] = fv.x; af32[g * 4 + 1] = fv.y;
      af32[g * 4 + 2] = fv.z; af32[g * 4 + 3] = fv.w;
    }
    if (PIXT) {
#pragma unroll
      for (int j = 0; j < 16; ++j) af32[j] = 2.f * (af32[j] - 0.5f);
    }
    const float* gb = B + (size_t)(k0 + bk0) * N + (n0 + bnn);
    float bv[16];
#pragma unroll
    for (int j = 0; j < 16; ++j) bv[j] = gb[(size_t)j * N];

    ushort_t au[16];
#pragma unroll
    for (int j = 0; j < 16; ++j) au[j] = f2bf(af32[j]);
    *(uint4*)(&Asm[arow][acol]) = *(const uint4*)(&au[0]);
    *(uint4*)(&Asm[arow][acol + 8]) = *(const uint4*)(&au[8]);
#pragma unroll
    for (int g = 0; g < 4; ++g) {
      ushort4 w;
      w.x = f2bf(bv[g * 4 + 0]);
      w.y = f2bf(bv[g * 4 + 1]);
      w.z = f2bf(bv[g * 4 + 2]);
      w.w = f2bf(bv[g * 4 + 3]);
      *(ushort4*)(&Bsm[bnn][bk0 + (g << 2)]) = w;
    }
    __syncthreads();
    frag8 af[4], bfr[4];
#pragma unroll
    for (int i = 0; i < 4; ++i) af[i] = *(const frag8*)(&Asm[wm + i * 16 + l15][lg << 3]);
#pragma unroll
    for (int i = 0; i < 4; ++i) bfr[i] = *(const frag8*)(&Bsm[wn + i * 16 + l15][lg << 3]);
#pragma unroll
    for (int mi = 0; mi < 4; ++mi)
#pragma unroll
      for (int ni = 0; ni < 4; ++ni)
        acc[mi][ni] = __builtin_amdgcn_mfma_f32_16x16x32_bf16(af[mi], bfr[ni], acc[mi][ni], 0, 0, 0);
    __syncthreads();
  }

#pragma unroll
  for (int mi = 0; mi < 4; ++mi) {
#pragma unroll
    for (int ni = 0; ni < 4; ++ni) {
#pragma unroll
      for (int r = 0; r < 4; ++r) {
        float val = acc[mi][ni][r];
        if (EPI == EPI_RAW) {
          C[(size_t)tid * 64 + (mi * 4 + ni) * 4 + r] = val;
          continue;
        }
        int gr = m0 + wm + mi * 16 + (lg << 2) + r;
        int gc = n0 + wn + ni * 16 + l15;
        size_t idx = (size_t)gr * N + gc;
        if (EPI == EPI_F32) {
          C[idx] = val;
        } else if (EPI == EPI_ADDF32) {
          C[idx] += val;
        } else if (EPI == EPI_GELU) {
          float x3 = val * val * val;
          float g = 0.5f * val * (1.f + tanhf(0.7978845608028654f * (val + 0.044715f * x3)));
          C[idx] = g;
        } else if (EPI == EPI_MUL) {
          C[idx] = val * Mul[idx];
        }
      }
    }
  }
}

// ---------------- bf16-exact VALU reference for the 128x128 probe ----------------
__global__ __launch_bounds__(256) void k_refgemm(const float* __restrict__ A,
                                                 const float* __restrict__ B,
                                                 float* __restrict__ Cref) {
  int idx = blockIdx.x * 256 + threadIdx.x;  // 0..16383
  int r = idx >> 7, c = idx & 127;
  float s = 0.f;
  for (int k = 0; k < 1024; ++k) {
    float a = bf2f(f2bf(A[(size_t)r * 1024 + k]));
    float b = bf2f(f2bf(B[(size_t)k * 1024 + c]));
    s += a * b;
  }
  Cref[idx] = s;
}

// ---------------- judge: count H1 mismatches + locate probes in raw regs ----------------
__global__ void k_judge(const float* __restrict__ Cm,   // stride 1024
                        const float* __restrict__ Cref, // stride 128
                        const float* __restrict__ raw,  // [256][64]
                        float* dout) {
  int count = 0;
  for (int r = 0; r < 128; ++r)
    for (int c = 0; c < 128; ++c) {
      float d = Cm[(size_t)r * 1024 + c] - Cref[r * 128 + c];
      if (fabsf(d) > 1e-5f) count++;
    }
  float tg[2];
  tg[0] = Cref[1 * 128 + 0];  // C[1][0]
  tg[1] = Cref[0 * 128 + 9];  // C[0][9]
  int p[2] = {255, 255};
  for (int pi = 0; pi < 2; ++pi) {
    // scan wave 0, fragment (mi=0,ni=0): raw[t*64 + 0 + r], t=0..63
    for (int t = 0; t < 64 && p[pi] == 255; ++t)
      for (int rr = 0; rr < 4; ++rr)
        if (fabsf(raw[t * 64 + rr] - tg[pi]) < 2e-6f) { p[pi] = t * 4 + rr; break; }
    if (p[pi] == 255) {  // fallback: anywhere in the dump?
      for (int i = 0; i < 16384; ++i)
        if (fabsf(raw[i] - tg[pi]) < 2e-6f) { p[pi] = 254; break; }
    }
  }
  if (count > 0) {
    int bucket = (count < 16) ? 0 : (count < 2048 ? 1 : 2);
    dout[0] = (float)((p[0] * 256 + p[1]) * 1000 + bucket * 300);
  }
}

// ---------------- simple exact attention f32 ----------------
__global__ __launch_bounds__(256) void k_attn32(const float* __restrict__ q,
                                                const float* __restrict__ k,
                                                const float* __restrict__ v,
                                                float* __restrict__ o) {
  __shared__ float qs[64];
  __shared__ float ps[1024];
  __shared__ float red[8];
  __shared__ float part[16][64];
  const int tid = threadIdx.x;
  const int l = blockIdx.x;
  const int bh = blockIdx.y;
  const int b = bh >> 4, n = bh & 15;
  const size_t base = (size_t)b * 1048576 + (size_t)n * 64;
  const size_t qoff = base + (size_t)l * 1024;
  if (tid < 64) qs[tid] = q[qoff + tid];
  __syncthreads();

  float sv[4];
  float lmax = -3.0e38f;
#pragma unroll
  for (int j = 0; j < 4; ++j) {
    int kk = (tid << 2) + j;
    const float* krow = k + base + (size_t)kk * 1024;
    float s = 0.f;
#pragma unroll
    for (int c = 0; c < 64; c += 4) {
      float4 kv = *(const float4*)(krow + c);
      s += qs[c + 0] * kv.x + qs[c + 1] * kv.y + qs[c + 2] * kv.z + qs[c + 3] * kv.w;
    }
    sv[j] = s;
    lmax = fmaxf(lmax, s);
  }
  for (int m = 1; m < 64; m <<= 1) lmax = fmaxf(lmax, __shfl_xor(lmax, m));
  if ((tid & 63) == 0) red[tid >> 6] = lmax;
  __syncthreads();
  float smax = fmaxf(fmaxf(red[0], red[1]), fmaxf(red[2], red[3]));
  float lsum = 0.f;
#pragma unroll
  for (int j = 0; j < 4; ++j) {
    float p = expf(sv[j] - smax);
    ps[(tid << 2) + j] = p;
    lsum += p;
  }
  for (int m = 1; m < 64; m <<= 1) lsum += __shfl_xor(lsum, m);
  if ((tid & 63) == 0) red[4 + (tid >> 6)] = lsum;
  __syncthreads();
  float ssum = red[4] + red[5] + red[6] + red[7];

  const int kp = tid >> 4, hg = tid & 15;
  float a0 = 0.f, a1 = 0.f, a2 = 0.f, a3 = 0.f;
  for (int kk = kp << 6; kk < (kp << 6) + 64; ++kk) {
    float p = ps[kk];
    float4 vv = *(const float4*)(v + base + (size_t)kk * 1024 + (hg << 2));
    a0 += p * vv.x; a1 += p * vv.y; a2 += p * vv.z; a3 += p * vv.w;
  }
  part[kp][hg * 4 + 0] = a0;
  part[kp][hg * 4 + 1] = a1;
  part[kp][hg * 4 + 2] = a2;
  part[kp][hg * 4 + 3] = a3;
  __syncthreads();
  if (tid < 64) {
    float s = 0.f;
#pragma unroll
    for (int i = 0; i < 16; ++i) s += part[i][tid];
    o[qoff + tid] = s / ssum;
  }
}

// ---------------- 4x4 pooling + mask ----------------
__global__ __launch_bounds__(256) void k_pool(const float* __restrict__ x,
                                              const int* __restrict__ pos,
                                              float* __restrict__ out,
                                              float* __restrict__ maskout) {
  __shared__ int smax[4];
  __shared__ int kidx_s[1024];
  const int blk = blockIdx.x;
  const int b = blk >> 6, oidx = blk & 63;
  const int tid = threadIdx.x;
  int mx = 0;
  for (int l = tid; l < 1024; l += 256) {
    int p0 = pos[((size_t)b * 1024 + l) * 2];
    mx = max(mx, p0 > 0 ? p0 : 0);
  }
  for (int m = 1; m < 64; m <<= 1) mx = max(mx, __shfl_xor(mx, m));
  if ((tid & 63) == 0) smax[tid >> 6] = mx;
  __syncthreads();
  int maxx = max(max(smax[0], smax[1]), max(smax[2], smax[3])) + 1;
  int mk = maxx >> 2;
  for (int l = tid; l < 1024; l += 256) {
    int p0 = pos[((size_t)b * 1024 + l) * 2];
    int p1 = pos[((size_t)b * 1024 + l) * 2 + 1];
    int c0 = p0 > 0 ? p0 : 0, c1 = p1 > 0 ? p1 : 0;
    int pad = (p0 == -1 && p1 == -1) ? 1 : 0;
    kidx_s[l] = ((c0 >> 2) + mk * (c1 >> 2)) | (pad << 16);
  }
  __syncthreads();
  float ax = 0.f, ay = 0.f, az = 0.f, aw = 0.f;
  int cnt = 0;
  for (int l = 0; l < 1024; ++l) {
    int ki = kidx_s[l];
    if ((ki & 0xffff) == oidx) {
      cnt++;
      if (!(ki >> 16)) {
        float4 xv = ((const float4*)(x + ((size_t)b * 1024 + l) * 1024))[tid];
        ax += xv.x; ay += xv.y; az += xv.z; aw += xv.w;
      }
    }
  }
  float4 res;
  res.x = ax * 2.0f; res.y = ay * 2.0f; res.z = az * 2.0f; res.w = aw * 2.0f;
  ((float4*)(out + ((size_t)b * 64 + oidx) * 1024))[tid] = res;
  if (tid == 0) maskout[b * 64 + oidx] = (cnt > 0) ? 1.0f : 0.0f;
}

// ---------------- host launch ----------------
extern "C" void kernel_launch(void* const* d_in, const int* in_sizes, int n_in,
                              void* d_out, int out_size, void* d_ws, size_t ws_size,
                              hipStream_t stream) {
  const float* pix = (const float*)d_in[0];
  const int* pos = (const int*)d_in[1];
  const float* Win = (const float*)d_in[2];
  const float* ptab = (const float*)d_in[3];
  const float* Wq = (const float*)d_in[4];
  const float* Wk = (const float*)d_in[5];
  const float* Wv = (const float*)d_in[6];
  const float* Wo = (const float*)d_in[7];
  const float* qn = (const float*)d_in[8];
  const float* kn = (const float*)d_in[9];
  const float* pre_attn = (const float*)d_in[10];
  const float* post_attn = (const float*)d_in[11];
  const float* pre_ffw = (const float*)d_in[12];
  const float* post_ffw = (const float*)d_in[13];
  const float* Wg = (const float*)d_in[14];
  const float* Wu = (const float*)d_in[15];
  const float* Wd = (const float*)d_in[16];

  char* w = (char*)d_ws;
  float* x = (float*)w;   w += 16777216;
  float* tmp = (float*)w; w += 16777216;
  float* h = (float*)w;   w += 16777216;
  float* qb = (float*)w;  w += 16777216;
  float* kb = (float*)w;  w += 16777216;
  float* vb = (float*)w;  w += 16777216;
  float* ab = (float*)w;  w += 16777216;
  float* gb = (float*)w;  w += 67108864;
  float* diagC = (float*)w;   w += 524288;   // 128 rows x 1024 stride
  float* diagRef = (float*)w; w += 65536;    // 128x128
  float* diagRaw = (float*)w; w += 65536;    // 256 threads x 64

  dim3 blk(256);
  k_posemb<<<4096, blk, 0, stream>>>(pos, ptab, x);
  k_gemm32<EPI_ADDF32, true><<<dim3(16, 64), blk, 0, stream>>>(pix, Win, x, nullptr, 768, 1024);

  for (int i = 0; i < 6; ++i) {
    const float* wq = Wq + (size_t)i * 1048576;
    const float* wk = Wk + (size_t)i * 1048576;
    const float* wv = Wv + (size_t)i * 1048576;
    const float* wo = Wo + (size_t)i * 1048576;
    const float* wg = Wg + (size_t)i * 4194304;
    const float* wu = Wu + (size_t)i * 4194304;
    const float* wd = Wd + (size_t)i * 4194304;

    k_rmsnorm32<<<4096, blk, 0, stream>>>(x, pre_attn + i * 1024, h);
    k_gemm32<EPI_F32, false><<<dim3(16, 64), blk, 0, stream>>>(h, wq, tmp, nullptr, 1024, 1024);
    k_qknorm32<true><<<4096, blk, 0, stream>>>(tmp, qn + i * 64, pos, qb);
    k_gemm32<EPI_F32, false><<<dim3(16, 64), blk, 0, stream>>>(h, wk, tmp, nullptr, 1024, 1024);
    k_qknorm32<true><<<4096, blk, 0, stream>>>(tmp, kn + i * 64, pos, kb);
    k_gemm32<EPI_F32, false><<<dim3(16, 64), blk, 0, stream>>>(h, wv, tmp, nullptr, 1024, 1024);
    k_qknorm32<false><<<4096, blk, 0, stream>>>(tmp, nullptr, pos, vb);
    k_attn32<<<dim3(1024, 64), blk, 0, stream>>>(qb, kb, vb, ab);
    k_gemm32<EPI_F32, false><<<dim3(16, 64), blk, 0, stream>>>(ab, wo, tmp, nullptr, 1024, 1024);
    k_addrms32<<<4096, blk, 0, stream>>>(x, tmp, post_attn + i * 1024);

    k_rmsnorm32<<<4096, blk, 0, stream>>>(x, pre_ffw + i * 1024, h);
    k_gemm32<EPI_GELU, false><<<dim3(64, 64), blk, 0, stream>>>(h, wg, gb, nullptr, 1024, 4096);
    k_gemm32<EPI_MUL, false><<<dim3(64, 64), blk, 0, stream>>>(h, wu, gb, gb, 1024, 4096);
    k_gemm32<EPI_F32, false><<<dim3(16, 64), blk, 0, stream>>>(gb, wd, tmp, nullptr, 4096, 1024);
    k_addrms32<<<4096, blk, 0, stream>>>(x, tmp, post_ffw + i * 1024);
  }

  k_pool<<<256, blk, 0, stream>>>(x, pos, (float*)d_out, (float*)d_out + 262144);

  // ---------------- MFMA diagnostic probe (after pool; only touches d_out[0] if broken) ----------------
  k_gemmx<EPI_F32, false><<<dim3(1, 1), blk, 0, stream>>>(Wq, Wk, diagC, nullptr, 1024, 1024);
  k_gemmx<EPI_RAW, false><<<dim3(1, 1), blk, 0, stream>>>(Wq, Wk, diagRaw, nullptr, 1024, 1024);
  k_refgemm<<<64, blk, 0, stream>>>(Wq, Wk, diagRef);
  k_judge<<<1, 1, 0, stream>>>(diagC, diagRef, diagRaw, (float*)d_out);
}